// Round 1
// baseline (3841.010 us; speedup 1.0000x reference)
//
#include <hip/hip_runtime.h>
#include <math.h>

#define BB 8
#define TT 12
#define NN 716
#define EE 10
#define HH 64
#define DIN 65
#define OG 128
#define OU 64
#define XSP 68     // padded xs row stride
#define GP 720     // padded graph row stride
#define JSPLIT 16
#define JLEN 45    // ceil(716/16)
#define NT3 128
#define NC3 6      // ceil(716/128)

__device__ __forceinline__ float sigmf(float x){ return 1.0f/(1.0f+__expf(-x)); }

// ---------------- emb precompute + cur0 ----------------
__global__ void k_emb(const float* __restrict__ src, const float* __restrict__ ne,
                      const float* __restrict__ te, const float* __restrict__ de,
                      float* __restrict__ emb, float* __restrict__ cur){
  int idx = blockIdx.x*256 + threadIdx.x;
  if (idx >= BB*TT*NN) return;
  int n = idx % NN; int t = (idx/NN) % TT; int b = idx/(NN*TT);
  const float* s = src + (size_t)idx*3;
  float x = s[0];
  int ti = (int)(s[1]*288.0f);
  int di = (int)(s[2]);
  size_t eo = ((size_t)b*TT + t)*NN*EE + (size_t)n*EE;
  #pragma unroll
  for (int e=0;e<EE;e++)
    emb[eo+e] = ne[n*EE+e]*te[ti*EE+e]*de[di*EE+e];
  cur[((size_t)t*BB + b)*NN + n] = x;   // cur[0][t][b][n]
}

// ---------------- per-layer w = static@wp, b = static@bp ----------------
__global__ void k_prep_w(const float* __restrict__ ne, const float* __restrict__ wp,
                         const float* __restrict__ bp, float* __restrict__ w,
                         float* __restrict__ bias, int O){
  long idx = (long)blockIdx.x*256 + threadIdx.x;
  long totw = (long)NN*2*DIN*O;
  if (idx < totw){
    int o = (int)(idx % O); long r = idx / O;
    int i = (int)(r % DIN); r /= DIN;
    int k = (int)(r % 2); int n = (int)(r / 2);
    float acc = 0.f;
    #pragma unroll
    for (int e=0;e<EE;e++)
      acc += ne[n*EE+e]*wp[(((long)e*2+k)*DIN+i)*O+o];
    w[idx] = acc;
  } else if (idx < totw + (long)NN*O){
    long j = idx - totw; int o = (int)(j % O); int n = (int)(j / O);
    float acc = 0.f;
    #pragma unroll
    for (int e=0;e<EE;e++) acc += ne[n*EE+e]*bp[e*O+o];
    bias[j] = acc;
  }
}

// ---------------- t=0: xs=[x,0], gate-MLP -> nv ----------------
__global__ void k_init(const float* __restrict__ cur_c,
                       const float* __restrict__ f1W, const float* __restrict__ f1b,
                       const float* __restrict__ f2W, const float* __restrict__ f2b,
                       const float* __restrict__ f3W, const float* __restrict__ f3b,
                       const float* __restrict__ emb,
                       float* __restrict__ xsg, float* __restrict__ nv){
  int idx = blockIdx.x*256 + threadIdx.x;
  if (idx >= BB*NN) return;
  int b = idx / NN, n = idx % NN;
  float x = cur_c[(size_t)b*NN + n];   // t = 0
  float* xr = xsg + (size_t)idx*XSP;
  xr[0] = x;
  #pragma unroll
  for (int i=1;i<DIN;i++) xr[i] = 0.f;
  xr[65]=0.f; xr[66]=0.f; xr[67]=0.f;
  float h1[16];
  #pragma unroll
  for (int k=0;k<16;k++) h1[k] = sigmf(f1b[k] + f1W[k*DIN]*x);
  float h2[2];
  #pragma unroll
  for (int k=0;k<2;k++){
    float s = f2b[k];
    #pragma unroll
    for (int q=0;q<16;q++) s += f2W[k*16+q]*h1[q];
    h2[k] = sigmf(s);
  }
  #pragma unroll
  for (int e=0;e<EE;e++){
    float xe = f3b[e] + f3W[e*2]*h2[0] + f3W[e*2+1]*h2[1];
    nv[(size_t)idx*EE+e] = tanhf(emb[((size_t)b*TT+0)*NN*EE + (size_t)n*EE + e]*xe);
  }
}

// ---------------- graph rows + rowsum^-1/2 ----------------
__global__ void k_rowsum(const float* __restrict__ nv, float* __restrict__ G,
                         float* __restrict__ d){
  int row = blockIdx.x*4 + (threadIdx.x>>6);
  int lane = threadIdx.x & 63;
  if (row >= BB*NN) return;
  int b = row / NN;
  float a[EE];
  #pragma unroll
  for (int e=0;e<EE;e++) a[e] = nv[(size_t)row*EE+e];
  const float* nvb = nv + (size_t)b*NN*EE;
  float* Gr = G + (size_t)row*GP;
  float sum = 0.f;
  for (int jb=0; jb<NN; jb+=64){
    int j = jb + lane;
    if (j < NN){
      const float* q = nvb + (size_t)j*EE;
      float s = 0.f;
      #pragma unroll
      for (int e=0;e<EE;e++) s += a[e]*q[e];
      s = fmaxf(s, 0.f);
      Gr[j] = s;
      sum += s;
    }
  }
  #pragma unroll
  for (int m=32;m;m>>=1) sum += __shfl_xor(sum, m, 64);
  if (lane==0) d[row] = rsqrtf(sum);
}

// ---------------- split-K GEMM: parts[js][b][n][i<64] = sum_j G[b,n,j]*d_j*xs[b,j,i] ----------------
__global__ __launch_bounds__(256) void k_gemm(const float* __restrict__ G,
                      const float* __restrict__ d, const float* __restrict__ xs,
                      float* __restrict__ parts){
  __shared__ float gs[64][128];
  __shared__ float xss[64][64];
  int js = blockIdx.x, nc = blockIdx.y, b = blockIdx.z;
  int tid = threadIdx.x;
  int w = tid >> 6, lane = tid & 63;
  int n0 = nc*NT3;
  int j0 = js*JLEN, jend = min(NN, j0+JLEN);
  float acc[32];
  #pragma unroll
  for (int k=0;k<32;k++) acc[k]=0.f;
  for (int jc=j0; jc<jend; jc+=64){
    int cn = min(64, jend-jc);
    for (int idx=tid; idx<64*128; idx+=256){
      int jj = idx>>7, nn2 = idx&127;
      int n = n0+nn2;
      gs[jj][nn2] = (jj<cn && n<NN) ? G[((size_t)b*NN + jc+jj)*GP + n] : 0.f;
    }
    for (int idx=tid; idx<64*64; idx+=256){
      int jj = idx>>6, ii = idx&63;
      int j = jc+jj;
      xss[jj][ii] = (jj<cn) ? d[b*NN+j]*xs[((size_t)b*NN+j)*XSP+ii] : 0.f;
    }
    __syncthreads();
    for (int jj=0; jj<cn; ++jj){
      float xv = xss[jj][lane];
      const float4* gp = (const float4*)&gs[jj][w*32];
      #pragma unroll
      for (int q=0;q<8;q++){
        float4 g = gp[q];
        acc[q*4+0] += g.x*xv;
        acc[q*4+1] += g.y*xv;
        acc[q*4+2] += g.z*xv;
        acc[q*4+3] += g.w*xv;
      }
    }
    __syncthreads();
  }
  for (int k=0;k<32;k++){
    int n = n0 + w*32 + k;
    if (n < NN) parts[(((size_t)js*BB + b)*NN + n)*64 + lane] = acc[k];
  }
}

// ---------------- gate transform: zr=sigmoid(...), cand -> xsu, update-MLP -> nv ----------------
__global__ __launch_bounds__(256) void k_tr_gate(
    const float* __restrict__ wg, const float* __restrict__ bg,
    const float* __restrict__ parts, const float* __restrict__ d,
    const float* __restrict__ G, const float* __restrict__ xsg,
    const float* __restrict__ cur_ct, const float* __restrict__ h,
    const float* __restrict__ emb, int t,
    const float* __restrict__ f1W, const float* __restrict__ f1b,
    const float* __restrict__ f2W, const float* __restrict__ f2b,
    const float* __restrict__ f3W, const float* __restrict__ f3b,
    float* __restrict__ rbuf, float* __restrict__ xsu, float* __restrict__ nv)
{
  __shared__ float xg2s[BB][64];
  __shared__ float xg64[BB];
  __shared__ float xss[BB][DIN];
  __shared__ float cs[BB][DIN];
  __shared__ float h1s[BB][16];
  __shared__ float h2s[BB][2];
  int n = blockIdx.x;
  int tid = threadIdx.x;
  // ---- phase A: gather xg2 rows (split-K reduce + d_n scale), xs rows, col-64 fixup
  for (int idx=tid; idx<BB*64; idx+=256){
    int b = idx>>6, i = idx&63;
    float s = 0.f;
    #pragma unroll
    for (int js2=0; js2<JSPLIT; js2++)
      s += parts[(((size_t)js2*BB + b)*NN + n)*64 + i];
    xg2s[b][i] = d[b*NN+n]*s;
  }
  for (int idx=tid; idx<BB*DIN; idx+=256){
    int b = idx/DIN, i = idx%DIN;
    xss[b][i] = xsg[((size_t)b*NN+n)*XSP + i];
  }
  {
    int w = tid>>6, lane = tid&63;
    for (int b=w; b<BB; b+=4){
      const float* Gr = G + ((size_t)b*NN+n)*GP;
      float p = 0.f;
      for (int j=lane; j<NN; j+=64)
        p += Gr[j]*d[b*NN+j]*xsg[((size_t)b*NN+j)*XSP + 64];
      #pragma unroll
      for (int m=32;m;m>>=1) p += __shfl_xor(p, m, 64);
      if (lane==0) xg64[b] = d[b*NN+n]*p;
    }
  }
  __syncthreads();
  // ---- phase B: out = xs*w0 + xg2*w1 + b ; sigmoid ; z*h -> cand ; r -> rbuf
  {
    int o = tid & 127, half = tid >> 7;
    const float* w0p = wg + ((size_t)n*2+0)*DIN*OG + o;
    const float* w1p = wg + ((size_t)n*2+1)*DIN*OG + o;
    float acc[4];
    #pragma unroll
    for (int bb=0;bb<4;bb++) acc[bb] = bg[n*OG+o];
    for (int i=0;i<64;i++){
      float w0 = w0p[i*OG], w1 = w1p[i*OG];
      #pragma unroll
      for (int bb=0;bb<4;bb++){
        int b = 2*bb+half;
        acc[bb] += xss[b][i]*w0 + xg2s[b][i]*w1;
      }
    }
    {
      float w0 = w0p[64*OG], w1 = w1p[64*OG];
      #pragma unroll
      for (int bb=0;bb<4;bb++){
        int b = 2*bb+half;
        acc[bb] += xss[b][64]*w0 + xg64[b]*w1;
      }
    }
    #pragma unroll
    for (int bb=0;bb<4;bb++){
      int b = 2*bb+half;
      float v = sigmf(acc[bb]);
      if (o < 64){
        float cv = v * h[((size_t)b*NN+n)*HH + o];
        xsu[((size_t)b*NN+n)*XSP + 1 + o] = cv;
        cs[b][1+o] = cv;
      } else {
        rbuf[((size_t)b*NN+n)*HH + (o-64)] = v;
      }
    }
    if (o == 64){
      #pragma unroll
      for (int bb=0;bb<4;bb++){
        int b = 2*bb+half;
        float x = cur_ct[(size_t)b*NN+n];
        cs[b][0] = x;
        xsu[((size_t)b*NN+n)*XSP] = x;
      }
    }
  }
  __syncthreads();
  // ---- phase C: update-gcn small MLP -> nv
  if (tid < BB*16){
    int b = tid>>4, k = tid&15;
    const float* wrow = f1W + k*DIN;
    float s = f1b[k];
    #pragma unroll
    for (int i=0;i<DIN;i++) s += cs[b][i]*wrow[i];
    h1s[b][k] = sigmf(s);
  }
  __syncthreads();
  if (tid < BB*2){
    int b = tid>>1, k = tid&1;
    float s = f2b[k];
    #pragma unroll
    for (int q=0;q<16;q++) s += h1s[b][q]*f2W[k*16+q];
    h2s[b][k] = sigmf(s);
  }
  __syncthreads();
  if (tid < BB*EE){
    int b = tid/EE, e = tid%EE;
    float xe = f3b[e] + f3W[e*2]*h2s[b][0] + f3W[e*2+1]*h2s[b][1];
    nv[((size_t)b*NN+n)*EE + e] = tanhf(emb[((size_t)b*TT+t)*NN*EE + (size_t)n*EE + e]*xe);
  }
}

// ---------------- update transform: hc=tanh, h=r*h+(1-r)*hc; next-step gate MLP OR pred/skip ----------------
__global__ __launch_bounds__(256) void k_tr_upd(
    const float* __restrict__ wu, const float* __restrict__ bu,
    const float* __restrict__ parts, const float* __restrict__ d,
    const float* __restrict__ G, const float* __restrict__ xsu,
    const float* __restrict__ rbuf, float* __restrict__ h,
    float* __restrict__ cur, int c, int t,
    const float* __restrict__ emb,
    const float* __restrict__ f1W, const float* __restrict__ f1b,
    const float* __restrict__ f2W, const float* __restrict__ f2b,
    const float* __restrict__ f3W, const float* __restrict__ f3b,
    float* __restrict__ xsg, float* __restrict__ nv,
    const float* __restrict__ predW, const float* __restrict__ predB,
    const float* __restrict__ skipW, const float* __restrict__ skipB,
    float* __restrict__ out)
{
  __shared__ float xg2s[BB][64];
  __shared__ float xg64[BB];
  __shared__ float xss[BB][DIN];
  __shared__ float hs[BB][HH];
  __shared__ float h1s[BB][16];
  __shared__ float h2s[BB][2];
  __shared__ float xns[BB];
  int n = blockIdx.x;
  int tid = threadIdx.x;
  // ---- phase A
  for (int idx=tid; idx<BB*64; idx+=256){
    int b = idx>>6, i = idx&63;
    float s = 0.f;
    #pragma unroll
    for (int js2=0; js2<JSPLIT; js2++)
      s += parts[(((size_t)js2*BB + b)*NN + n)*64 + i];
    xg2s[b][i] = d[b*NN+n]*s;
  }
  for (int idx=tid; idx<BB*DIN; idx+=256){
    int b = idx/DIN, i = idx%DIN;
    xss[b][i] = xsu[((size_t)b*NN+n)*XSP + i];
  }
  {
    int w = tid>>6, lane = tid&63;
    for (int b=w; b<BB; b+=4){
      const float* Gr = G + ((size_t)b*NN+n)*GP;
      float p = 0.f;
      for (int j=lane; j<NN; j+=64)
        p += Gr[j]*d[b*NN+j]*xsu[((size_t)b*NN+j)*XSP + 64];
      #pragma unroll
      for (int m=32;m;m>>=1) p += __shfl_xor(p, m, 64);
      if (lane==0) xg64[b] = d[b*NN+n]*p;
    }
  }
  __syncthreads();
  // ---- phase B
  {
    int o = tid & 63, grp = tid >> 6;
    const float* w0p = wu + ((size_t)n*2+0)*DIN*OU + o;
    const float* w1p = wu + ((size_t)n*2+1)*DIN*OU + o;
    float acc[2];
    acc[0] = bu[n*OU+o]; acc[1] = acc[0];
    for (int i=0;i<64;i++){
      float w0 = w0p[i*OU], w1 = w1p[i*OU];
      #pragma unroll
      for (int bb=0;bb<2;bb++){
        int b = grp + 4*bb;
        acc[bb] += xss[b][i]*w0 + xg2s[b][i]*w1;
      }
    }
    {
      float w0 = w0p[64*OU], w1 = w1p[64*OU];
      #pragma unroll
      for (int bb=0;bb<2;bb++){
        int b = grp + 4*bb;
        acc[bb] += xss[b][64]*w0 + xg64[b]*w1;
      }
    }
    #pragma unroll
    for (int bb=0;bb<2;bb++){
      int b = grp + 4*bb;
      float hc = tanhf(acc[bb]);
      float r = rbuf[((size_t)b*NN+n)*HH+o];
      float hold = h[((size_t)b*NN+n)*HH+o];
      float hn = r*hold + (1.f-r)*hc;
      h[((size_t)b*NN+n)*HH+o] = hn;
      hs[b][o] = hn;
    }
  }
  __syncthreads();
  if (t < TT-1){
    // ---- build next xs + gate MLP -> nv
    if (tid < BB){
      float x = cur[(((size_t)c*TT + (t+1))*BB + tid)*NN + n];
      xns[tid] = x;
      xsg[((size_t)tid*NN+n)*XSP] = x;
    }
    for (int idx=tid; idx<BB*HH; idx+=256){
      int b = idx>>6, oo = idx&63;
      xsg[((size_t)b*NN+n)*XSP + 1 + oo] = hs[b][oo];
    }
    __syncthreads();
    if (tid < BB*16){
      int b = tid>>4, k = tid&15;
      const float* wrow = f1W + k*DIN;
      float s = f1b[k] + wrow[0]*xns[b];
      #pragma unroll
      for (int oo=0;oo<HH;oo++) s += hs[b][oo]*wrow[1+oo];
      h1s[b][k] = sigmf(s);
    }
    __syncthreads();
    if (tid < BB*2){
      int b = tid>>1, k = tid&1;
      float s = f2b[k];
      #pragma unroll
      for (int q=0;q<16;q++) s += h1s[b][q]*f2W[k*16+q];
      h2s[b][k] = sigmf(s);
    }
    __syncthreads();
    if (tid < BB*EE){
      int b = tid/EE, e = tid%EE;
      float xe = f3b[e] + f3W[e*2]*h2s[b][0] + f3W[e*2+1]*h2s[b][1];
      nv[((size_t)b*NN+n)*EE + e] =
        tanhf(emb[((size_t)b*TT+(t+1))*NN*EE + (size_t)n*EE + e]*xe);
    }
  } else {
    // ---- final step: pred (+ skip & cur1 for c==0)
    if (tid < BB*TT){
      int b = tid/TT, ot = tid%TT;
      const float* pw = predW + ((size_t)c*TT + ot)*HH;
      float pv = predB[c*TT+ot];
      #pragma unroll
      for (int q=0;q<HH;q++) pv += hs[b][q]*pw[q];
      size_t oi = ((size_t)b*TT+ot)*NN + n;
      if (c == 0){
        out[oi] = pv;
        const float* sw = skipW + (size_t)ot*HH;
        float sk = skipB[ot];
        #pragma unroll
        for (int q=0;q<HH;q++) sk += hs[b][q]*sw[q];
        cur[(((size_t)1*TT+ot)*BB + b)*NN + n] =
            cur[(((size_t)0*TT+ot)*BB + b)*NN + n] - sk;
      } else {
        out[oi] += pv;
      }
    }
  }
}

extern "C" void kernel_launch(void* const* d_in, const int* in_sizes, int n_in,
                              void* d_out, int out_size, void* d_ws, size_t ws_size,
                              hipStream_t stream){
  const float* src  = (const float*)d_in[0];
  const float* ne   = (const float*)d_in[1];
  const float* te   = (const float*)d_in[2];
  const float* de   = (const float*)d_in[3];
  const float* wp_g = (const float*)d_in[4];
  const float* bp_g = (const float*)d_in[5];
  const float* f1W_g= (const float*)d_in[6];
  const float* f1b_g= (const float*)d_in[7];
  const float* f2W_g= (const float*)d_in[8];
  const float* f2b_g= (const float*)d_in[9];
  const float* f3W_g= (const float*)d_in[10];
  const float* f3b_g= (const float*)d_in[11];
  const float* wp_u = (const float*)d_in[12];
  const float* bp_u = (const float*)d_in[13];
  const float* f1W_u= (const float*)d_in[14];
  const float* f1b_u= (const float*)d_in[15];
  const float* f2W_u= (const float*)d_in[16];
  const float* f2b_u= (const float*)d_in[17];
  const float* f3W_u= (const float*)d_in[18];
  const float* f3b_u= (const float*)d_in[19];
  const float* predW= (const float*)d_in[20];
  const float* predB= (const float*)d_in[21];
  const float* skipW= (const float*)d_in[22];
  const float* skipB= (const float*)d_in[23];

  float* ws   = (float*)d_ws;
  float* emb  = ws;
  float* cur  = emb  + (size_t)BB*TT*NN*EE;
  float* wg   = cur  + (size_t)2*TT*BB*NN;
  float* bg   = wg   + (size_t)NN*2*DIN*OG;
  float* wu   = bg   + (size_t)NN*OG;
  float* bu   = wu   + (size_t)NN*2*DIN*OU;
  float* h    = bu   + (size_t)NN*OU;
  float* xsg  = h    + (size_t)BB*NN*HH;
  float* xsu  = xsg  + (size_t)BB*NN*XSP;
  float* nv   = xsu  + (size_t)BB*NN*XSP;
  float* dbuf = nv   + (size_t)BB*NN*EE;
  float* G    = dbuf + (size_t)BB*NN;
  float* parts= G    + (size_t)BB*NN*GP;
  float* rbuf = parts+ (size_t)JSPLIT*BB*NN*64;
  float* outp = (float*)d_out;

  k_emb<<<(BB*TT*NN+255)/256, 256, 0, stream>>>(src, ne, te, de, emb, cur);

  for (int c=0;c<2;c++){
    hipMemsetAsync(h, 0, (size_t)BB*NN*HH*sizeof(float), stream);
    {
      long tot = (long)NN*2*DIN*OG + (long)NN*OG;
      k_prep_w<<<(int)((tot+255)/256),256,0,stream>>>(
          ne, wp_g + (size_t)c*EE*2*DIN*OG, bp_g + (size_t)c*EE*OG, wg, bg, OG);
      long tot2 = (long)NN*2*DIN*OU + (long)NN*OU;
      k_prep_w<<<(int)((tot2+255)/256),256,0,stream>>>(
          ne, wp_u + (size_t)c*EE*2*DIN*OU, bp_u + (size_t)c*EE*OU, wu, bu, OU);
    }
    k_init<<<(BB*NN+255)/256,256,0,stream>>>(cur + (size_t)c*TT*BB*NN,
        f1W_g + c*16*DIN, f1b_g + c*16, f2W_g + c*2*16, f2b_g + c*2,
        f3W_g + c*EE*2, f3b_g + c*EE, emb, xsg, nv);
    for (int t=0;t<TT;t++){
      k_rowsum<<<BB*NN/4,256,0,stream>>>(nv, G, dbuf);
      k_gemm<<<dim3(JSPLIT,NC3,BB),256,0,stream>>>(G, dbuf, xsg, parts);
      k_tr_gate<<<NN,256,0,stream>>>(wg, bg, parts, dbuf, G, xsg,
          cur + ((size_t)c*TT+t)*BB*NN, h, emb, t,
          f1W_u + c*16*DIN, f1b_u + c*16, f2W_u + c*2*16, f2b_u + c*2,
          f3W_u + c*EE*2, f3b_u + c*EE, rbuf, xsu, nv);
      k_rowsum<<<BB*NN/4,256,0,stream>>>(nv, G, dbuf);
      k_gemm<<<dim3(JSPLIT,NC3,BB),256,0,stream>>>(G, dbuf, xsu, parts);
      k_tr_upd<<<NN,256,0,stream>>>(wu, bu, parts, dbuf, G, xsu, rbuf, h,
          cur, c, t, emb,
          f1W_g + c*16*DIN, f1b_g + c*16, f2W_g + c*2*16, f2b_g + c*2,
          f3W_g + c*EE*2, f3b_g + c*EE,
          xsg, nv, predW, predB, skipW, skipB, outp);
    }
  }
}

// Round 2
// 3319.109 us; speedup vs baseline: 1.1572x; 1.1572x over previous
//
#include <hip/hip_runtime.h>
#include <math.h>

#define BB 8
#define TT 12
#define NN 716
#define EE 10
#define HH 64
#define DIN 65
#define OG 128
#define OU 64
#define XSP 68     // padded xs / parts row stride
#define JS 8       // j-split for xg2 gemm
#define JR 90      // ceil(716/8)
#define TN 64      // n-tile in xg2 gemm
#define NC2 12     // ceil(716/64)
#define NP 768     // padded n for parts

__device__ __forceinline__ float sigmf(float x){ return 1.0f/(1.0f+__expf(-x)); }

// ---------------- emb precompute + cur0 ----------------
__global__ void k_emb(const float* __restrict__ src, const float* __restrict__ ne,
                      const float* __restrict__ te, const float* __restrict__ de,
                      float* __restrict__ emb, float* __restrict__ cur){
  int idx = blockIdx.x*256 + threadIdx.x;
  if (idx >= BB*TT*NN) return;
  int n = idx % NN; int t = (idx/NN) % TT; int b = idx/(NN*TT);
  const float* s = src + (size_t)idx*3;
  float x = s[0];
  int ti = (int)(s[1]*288.0f);
  int di = (int)(s[2]);
  size_t eo = ((size_t)b*TT + t)*NN*EE + (size_t)n*EE;
  #pragma unroll
  for (int e=0;e<EE;e++)
    emb[eo+e] = ne[n*EE+e]*te[ti*EE+e]*de[di*EE+e];
  cur[((size_t)t*BB + b)*NN + n] = x;   // cur[0][t][b][n]
}

// ---------------- per-layer w = static@wp (one block per (k,i) slab x n-half) ----------------
template<int O>
__global__ __launch_bounds__(256) void k_prep_w2(
    const float* __restrict__ ne, const float* __restrict__ wp,
    float* __restrict__ w)
{
  __shared__ float wps[EE][O];
  int ki = blockIdx.x;           // 0..129
  int half = blockIdx.y;         // 0..1
  int k = ki / DIN, i = ki - k*DIN;
  int tid = threadIdx.x;
  for (int idx=tid; idx<EE*O; idx+=256){
    int e = idx / O, o = idx - e*O;
    wps[e][o] = wp[(((size_t)e*2+k)*DIN+i)*O + o];
  }
  __syncthreads();
  constexpr int NG = 256/O;
  int o = tid & (O-1), ng = tid / O;
  int nend = min(NN, half*358+358);
  for (int n = half*358 + ng; n < nend; n += NG){
    float acc = 0.f;
    #pragma unroll
    for (int e=0;e<EE;e++) acc += ne[n*EE+e]*wps[e][o];
    w[(((size_t)n*2+k)*DIN+i)*O + o] = acc;
  }
}

template<int O>
__global__ void k_prep_b(const float* __restrict__ ne, const float* __restrict__ bp,
                         float* __restrict__ bias){
  int idx = blockIdx.x*256 + threadIdx.x;
  if (idx >= NN*O) return;
  int o = idx & (O-1), n = idx / O;
  float acc = 0.f;
  #pragma unroll
  for (int e=0;e<EE;e++) acc += ne[n*EE+e]*bp[e*O+o];
  bias[idx] = acc;
}

// ---------------- t=0: xs=[x,0], gate-MLP -> nv ----------------
__global__ void k_init(const float* __restrict__ cur_c,
                       const float* __restrict__ f1W, const float* __restrict__ f1b,
                       const float* __restrict__ f2W, const float* __restrict__ f2b,
                       const float* __restrict__ f3W, const float* __restrict__ f3b,
                       const float* __restrict__ emb,
                       float* __restrict__ xsg, float* __restrict__ nv){
  int idx = blockIdx.x*256 + threadIdx.x;
  if (idx >= BB*NN) return;
  int b = idx / NN, n = idx % NN;
  float x = cur_c[(size_t)b*NN + n];   // t = 0
  float* xr = xsg + (size_t)idx*XSP;
  xr[0] = x;
  #pragma unroll
  for (int i=1;i<XSP;i++) xr[i] = 0.f;
  float h1[16];
  #pragma unroll
  for (int k=0;k<16;k++) h1[k] = sigmf(f1b[k] + f1W[k*DIN]*x);
  float h2[2];
  #pragma unroll
  for (int k=0;k<2;k++){
    float s = f2b[k];
    #pragma unroll
    for (int q=0;q<16;q++) s += f2W[k*16+q]*h1[q];
    h2[k] = sigmf(s);
  }
  #pragma unroll
  for (int e=0;e<EE;e++){
    float xe = f3b[e] + f3W[e*2]*h2[0] + f3W[e*2+1]*h2[1];
    nv[(size_t)idx*EE+e] = tanhf(emb[((size_t)b*TT+0)*NN*EE + (size_t)n*EE + e]*xe);
  }
}

// ---------------- d only: d[b][j] = rsqrt(sum_n relu(nv_j . nv_n)) ----------------
__global__ __launch_bounds__(256) void k_dsum(const float* __restrict__ nv,
                                              float* __restrict__ d){
  __shared__ float c_nv[64][11];
  int jt = blockIdx.x, b = blockIdx.y;
  int tid = threadIdx.x;
  int jg = tid >> 4, ns = tid & 15;      // 4 j's per jg, 4 n's per ns per chunk
  int jbase = jt*64 + jg*4;
  float a[4][EE];
  #pragma unroll
  for (int r=0;r<4;r++){
    int j = jbase + r;
    #pragma unroll
    for (int e=0;e<EE;e++)
      a[r][e] = (j<NN) ? nv[((size_t)b*NN+j)*EE+e] : 0.f;
  }
  float sums[4] = {0.f,0.f,0.f,0.f};
  for (int ncc=0; ncc<NN; ncc+=64){
    int cnt = min(64, NN-ncc);
    __syncthreads();
    for (int idx=tid; idx<64*EE; idx+=256){
      int r = idx/EE, e = idx - r*EE;
      c_nv[r][e] = (r<cnt) ? nv[((size_t)b*NN+ncc+r)*EE+e] : 0.f;
    }
    __syncthreads();
    float g[4][4];
    #pragma unroll
    for (int r=0;r<4;r++){ g[r][0]=0;g[r][1]=0;g[r][2]=0;g[r][3]=0; }
    #pragma unroll
    for (int e=0;e<EE;e++){
      float c0=c_nv[ns*4+0][e], c1=c_nv[ns*4+1][e], c2=c_nv[ns*4+2][e], c3=c_nv[ns*4+3][e];
      #pragma unroll
      for (int r=0;r<4;r++){
        float av=a[r][e];
        g[r][0]+=av*c0; g[r][1]+=av*c1; g[r][2]+=av*c2; g[r][3]+=av*c3;
      }
    }
    #pragma unroll
    for (int r=0;r<4;r++)
      sums[r] += fmaxf(g[r][0],0.f)+fmaxf(g[r][1],0.f)+fmaxf(g[r][2],0.f)+fmaxf(g[r][3],0.f);
  }
  #pragma unroll
  for (int r=0;r<4;r++){
    float s = sums[r];
    s += __shfl_xor(s,1,64); s += __shfl_xor(s,2,64);
    s += __shfl_xor(s,4,64); s += __shfl_xor(s,8,64);
    sums[r] = s;
  }
  if (ns==0){
    #pragma unroll
    for (int r=0;r<4;r++){
      int j = jbase + r;
      if (j < NN) d[b*NN+j] = rsqrtf(sums[r]);
    }
  }
}

// ---------------- xg2 gemm, G on the fly: parts[js][b][n][i<=64] ----------------
__global__ __launch_bounds__(256) void k_xg2(
    const float* __restrict__ nv, const float* __restrict__ d,
    const float* __restrict__ xs, float* __restrict__ parts)
{
  __shared__ float a_nv[TN][11];
  __shared__ float b_nv[64][11];
  __shared__ float xss[64][XSP];
  __shared__ float gs[64][XSP];
  int nc = blockIdx.x, js = blockIdx.y, b = blockIdx.z;
  int tid = threadIdx.x;
  int n0 = nc*TN;
  int j0 = js*JR, jend = min(NN, j0+JR);
  // stage n-tile nv
  for (int idx=tid; idx<TN*EE; idx+=256){
    int r = idx/EE, e = idx - r*EE;
    int n = n0 + r;
    a_nv[r][e] = (n<NN) ? nv[((size_t)b*NN+n)*EE+e] : 0.f;
  }
  int ig = tid & 15, ng = tid >> 4;      // i = ig*4, n = ng*4 (main loop)
  int jg = tid >> 4, ng2 = tid & 15;     // gs-compute mapping
  int n2 = tid & 63, q = tid >> 6;       // col64 mapping
  float acc[4][4];
  #pragma unroll
  for (int r=0;r<4;r++){ acc[r][0]=0;acc[r][1]=0;acc[r][2]=0;acc[r][3]=0; }
  float a64p = 0.f;
  for (int jc=j0; jc<jend; jc+=64){
    int cnt = min(64, jend-jc);
    __syncthreads();
    // stage j-chunk nv + d_j-scaled xs
    for (int idx=tid; idx<64*EE; idx+=256){
      int r = idx/EE, e = idx - r*EE;
      b_nv[r][e] = (r<cnt) ? nv[((size_t)b*NN+jc+r)*EE+e] : 0.f;
    }
    for (int idx=tid; idx<64*64; idx+=256){
      int r = idx>>6, ii = idx&63;
      int j = jc + r;
      xss[r][ii] = (r<cnt) ? d[b*NN+j]*xs[((size_t)b*NN+j)*XSP+ii] : 0.f;
    }
    if (tid < 64){
      int j = jc + tid;
      xss[tid][64] = (tid<cnt) ? d[b*NN+j]*xs[((size_t)b*NN+j)*XSP+64] : 0.f;
    }
    __syncthreads();
    // compute gs tile = relu(nv_j . nv_n), 4x4 per thread
    {
      float g[4][4];
      #pragma unroll
      for (int r=0;r<4;r++){ g[r][0]=0;g[r][1]=0;g[r][2]=0;g[r][3]=0; }
      #pragma unroll
      for (int e=0;e<EE;e++){
        float b0=b_nv[jg*4+0][e], b1=b_nv[jg*4+1][e], b2=b_nv[jg*4+2][e], b3=b_nv[jg*4+3][e];
        float a0=a_nv[ng2*4+0][e], a1=a_nv[ng2*4+1][e], a2=a_nv[ng2*4+2][e], a3=a_nv[ng2*4+3][e];
        g[0][0]+=b0*a0; g[0][1]+=b0*a1; g[0][2]+=b0*a2; g[0][3]+=b0*a3;
        g[1][0]+=b1*a0; g[1][1]+=b1*a1; g[1][2]+=b1*a2; g[1][3]+=b1*a3;
        g[2][0]+=b2*a0; g[2][1]+=b2*a1; g[2][2]+=b2*a2; g[2][3]+=b2*a3;
        g[3][0]+=b3*a0; g[3][1]+=b3*a1; g[3][2]+=b3*a2; g[3][3]+=b3*a3;
      }
      #pragma unroll
      for (int r=0;r<4;r++){
        float4 v = { fmaxf(g[r][0],0.f), fmaxf(g[r][1],0.f),
                     fmaxf(g[r][2],0.f), fmaxf(g[r][3],0.f) };
        *(float4*)&gs[jg*4+r][ng2*4] = v;
      }
    }
    __syncthreads();
    // main accumulation
    for (int jj=0; jj<cnt; ++jj){
      float4 g4 = *(const float4*)&gs[jj][ng*4];
      float4 x4 = *(const float4*)&xss[jj][ig*4];
      acc[0][0]+=g4.x*x4.x; acc[0][1]+=g4.x*x4.y; acc[0][2]+=g4.x*x4.z; acc[0][3]+=g4.x*x4.w;
      acc[1][0]+=g4.y*x4.x; acc[1][1]+=g4.y*x4.y; acc[1][2]+=g4.y*x4.z; acc[1][3]+=g4.y*x4.w;
      acc[2][0]+=g4.z*x4.x; acc[2][1]+=g4.z*x4.y; acc[2][2]+=g4.z*x4.z; acc[2][3]+=g4.z*x4.w;
      acc[3][0]+=g4.w*x4.x; acc[3][1]+=g4.w*x4.y; acc[3][2]+=g4.w*x4.z; acc[3][3]+=g4.w*x4.w;
    }
    // col64 partials (gs rows >= cnt are zero)
    {
      float xv;
      #pragma unroll
      for (int r=0;r<16;r++){
        int jj = q*16 + r;
        xv = xss[jj][64];
        a64p += gs[jj][n2]*xv;
      }
    }
  }
  // write main acc
  #pragma unroll
  for (int r=0;r<4;r++){
    int n = n0 + ng*4 + r;
    float4 v = { acc[r][0], acc[r][1], acc[r][2], acc[r][3] };
    *(float4*)&parts[(((size_t)js*BB+b)*NP+n)*XSP + ig*4] = v;
  }
  // reduce + write col64
  __syncthreads();
  float* red = (float*)b_nv;
  red[q*64 + n2] = a64p;
  __syncthreads();
  if (tid < 64){
    float s = red[tid] + red[64+tid] + red[128+tid] + red[192+tid];
    parts[(((size_t)js*BB+b)*NP + n0+tid)*XSP + 64] = s;
  }
}

// ---------------- gate transform ----------------
__global__ __launch_bounds__(256) void k_tr_gate(
    const float* __restrict__ wg, const float* __restrict__ bg,
    const float* __restrict__ parts, const float* __restrict__ d,
    const float* __restrict__ xsg,
    const float* __restrict__ cur_ct, const float* __restrict__ h,
    const float* __restrict__ emb, int t,
    const float* __restrict__ f1W, const float* __restrict__ f1b,
    const float* __restrict__ f2W, const float* __restrict__ f2b,
    const float* __restrict__ f3W, const float* __restrict__ f3b,
    float* __restrict__ rbuf, float* __restrict__ xsu, float* __restrict__ nv)
{
  __shared__ float xg2s[BB][66];
  __shared__ float xss[BB][DIN];
  __shared__ float cs[BB][DIN];
  __shared__ float h1s[BB][16];
  __shared__ float h2s[BB][2];
  int n = blockIdx.x;
  int tid = threadIdx.x;
  for (int idx=tid; idx<BB*65; idx+=256){
    int b = idx/65, i = idx - b*65;
    float s = 0.f;
    #pragma unroll
    for (int js2=0; js2<JS; js2++)
      s += parts[(((size_t)js2*BB+b)*NP+n)*XSP + i];
    xg2s[b][i] = d[b*NN+n]*s;
  }
  for (int idx=tid; idx<BB*DIN; idx+=256){
    int b = idx/DIN, i = idx - b*DIN;
    xss[b][i] = xsg[((size_t)b*NN+n)*XSP + i];
  }
  __syncthreads();
  // phase B: out = xs*w0 + xg2*w1 + b ; sigmoid ; z*h -> cand ; r -> rbuf
  {
    int o = tid & 127, half = tid >> 7;
    const float* w0p = wg + ((size_t)n*2+0)*DIN*OG + o;
    const float* w1p = wg + ((size_t)n*2+1)*DIN*OG + o;
    float acc[4];
    #pragma unroll
    for (int bb=0;bb<4;bb++) acc[bb] = bg[n*OG+o];
    for (int i=0;i<65;i++){
      float w0 = w0p[i*OG], w1 = w1p[i*OG];
      #pragma unroll
      for (int bb=0;bb<4;bb++){
        int b = 2*bb+half;
        acc[bb] += xss[b][i]*w0 + xg2s[b][i]*w1;
      }
    }
    #pragma unroll
    for (int bb=0;bb<4;bb++){
      int b = 2*bb+half;
      float v = sigmf(acc[bb]);
      if (o < 64){
        float cv = v * h[((size_t)b*NN+n)*HH + o];
        xsu[((size_t)b*NN+n)*XSP + 1 + o] = cv;
        cs[b][1+o] = cv;
      } else {
        rbuf[((size_t)b*NN+n)*HH + (o-64)] = v;
      }
    }
    if (o == 64){
      #pragma unroll
      for (int bb=0;bb<4;bb++){
        int b = 2*bb+half;
        float x = cur_ct[(size_t)b*NN+n];
        cs[b][0] = x;
        xsu[((size_t)b*NN+n)*XSP] = x;
      }
    }
  }
  __syncthreads();
  // phase C: update-gcn small MLP -> nv
  if (tid < BB*16){
    int b = tid>>4, k = tid&15;
    const float* wrow = f1W + k*DIN;
    float s = f1b[k];
    #pragma unroll
    for (int i=0;i<DIN;i++) s += cs[b][i]*wrow[i];
    h1s[b][k] = sigmf(s);
  }
  __syncthreads();
  if (tid < BB*2){
    int b = tid>>1, k = tid&1;
    float s = f2b[k];
    #pragma unroll
    for (int q=0;q<16;q++) s += h1s[b][q]*f2W[k*16+q];
    h2s[b][k] = sigmf(s);
  }
  __syncthreads();
  if (tid < BB*EE){
    int b = tid/EE, e = tid%EE;
    float xe = f3b[e] + f3W[e*2]*h2s[b][0] + f3W[e*2+1]*h2s[b][1];
    nv[((size_t)b*NN+n)*EE + e] = tanhf(emb[((size_t)b*TT+t)*NN*EE + (size_t)n*EE + e]*xe);
  }
}

// ---------------- update transform ----------------
__global__ __launch_bounds__(256) void k_tr_upd(
    const float* __restrict__ wu, const float* __restrict__ bu,
    const float* __restrict__ parts, const float* __restrict__ d,
    const float* __restrict__ xsu,
    const float* __restrict__ rbuf, float* __restrict__ h,
    float* __restrict__ cur, int c, int t,
    const float* __restrict__ emb,
    const float* __restrict__ f1W, const float* __restrict__ f1b,
    const float* __restrict__ f2W, const float* __restrict__ f2b,
    const float* __restrict__ f3W, const float* __restrict__ f3b,
    float* __restrict__ xsg, float* __restrict__ nv,
    const float* __restrict__ predW, const float* __restrict__ predB,
    const float* __restrict__ skipW, const float* __restrict__ skipB,
    float* __restrict__ out)
{
  __shared__ float xg2s[BB][66];
  __shared__ float xss[BB][DIN];
  __shared__ float hs[BB][HH];
  __shared__ float h1s[BB][16];
  __shared__ float h2s[BB][2];
  __shared__ float xns[BB];
  int n = blockIdx.x;
  int tid = threadIdx.x;
  for (int idx=tid; idx<BB*65; idx+=256){
    int b = idx/65, i = idx - b*65;
    float s = 0.f;
    #pragma unroll
    for (int js2=0; js2<JS; js2++)
      s += parts[(((size_t)js2*BB+b)*NP+n)*XSP + i];
    xg2s[b][i] = d[b*NN+n]*s;
  }
  for (int idx=tid; idx<BB*DIN; idx+=256){
    int b = idx/DIN, i = idx - b*DIN;
    xss[b][i] = xsu[((size_t)b*NN+n)*XSP + i];
  }
  __syncthreads();
  // phase B
  {
    int o = tid & 63, grp = tid >> 6;
    const float* w0p = wu + ((size_t)n*2+0)*DIN*OU + o;
    const float* w1p = wu + ((size_t)n*2+1)*DIN*OU + o;
    float acc[2];
    acc[0] = bu[n*OU+o]; acc[1] = acc[0];
    for (int i=0;i<65;i++){
      float w0 = w0p[i*OU], w1 = w1p[i*OU];
      #pragma unroll
      for (int bb=0;bb<2;bb++){
        int b = grp + 4*bb;
        acc[bb] += xss[b][i]*w0 + xg2s[b][i]*w1;
      }
    }
    #pragma unroll
    for (int bb=0;bb<2;bb++){
      int b = grp + 4*bb;
      float hc = tanhf(acc[bb]);
      float r = rbuf[((size_t)b*NN+n)*HH+o];
      float hold = h[((size_t)b*NN+n)*HH+o];
      float hn = r*hold + (1.f-r)*hc;
      h[((size_t)b*NN+n)*HH+o] = hn;
      hs[b][o] = hn;
    }
  }
  __syncthreads();
  if (t < TT-1){
    if (tid < BB){
      float x = cur[(((size_t)c*TT + (t+1))*BB + tid)*NN + n];
      xns[tid] = x;
      xsg[((size_t)tid*NN+n)*XSP] = x;
    }
    for (int idx=tid; idx<BB*HH; idx+=256){
      int b = idx>>6, oo = idx&63;
      xsg[((size_t)b*NN+n)*XSP + 1 + oo] = hs[b][oo];
    }
    __syncthreads();
    if (tid < BB*16){
      int b = tid>>4, k = tid&15;
      const float* wrow = f1W + k*DIN;
      float s = f1b[k] + wrow[0]*xns[b];
      #pragma unroll
      for (int oo=0;oo<HH;oo++) s += hs[b][oo]*wrow[1+oo];
      h1s[b][k] = sigmf(s);
    }
    __syncthreads();
    if (tid < BB*2){
      int b = tid>>1, k = tid&1;
      float s = f2b[k];
      #pragma unroll
      for (int q=0;q<16;q++) s += h1s[b][q]*f2W[k*16+q];
      h2s[b][k] = sigmf(s);
    }
    __syncthreads();
    if (tid < BB*EE){
      int b = tid/EE, e = tid%EE;
      float xe = f3b[e] + f3W[e*2]*h2s[b][0] + f3W[e*2+1]*h2s[b][1];
      nv[((size_t)b*NN+n)*EE + e] =
        tanhf(emb[((size_t)b*TT+(t+1))*NN*EE + (size_t)n*EE + e]*xe);
    }
  } else {
    if (tid < BB*TT){
      int b = tid/TT, ot = tid%TT;
      const float* pw = predW + ((size_t)c*TT + ot)*HH;
      float pv = predB[c*TT+ot];
      #pragma unroll
      for (int q=0;q<HH;q++) pv += hs[b][q]*pw[q];
      size_t oi = ((size_t)b*TT+ot)*NN + n;
      if (c == 0){
        out[oi] = pv;
        const float* sw = skipW + (size_t)ot*HH;
        float sk = skipB[ot];
        #pragma unroll
        for (int q=0;q<HH;q++) sk += hs[b][q]*sw[q];
        cur[(((size_t)1*TT+ot)*BB + b)*NN + n] =
            cur[(((size_t)0*TT+ot)*BB + b)*NN + n] - sk;
      } else {
        out[oi] += pv;
      }
    }
  }
}

extern "C" void kernel_launch(void* const* d_in, const int* in_sizes, int n_in,
                              void* d_out, int out_size, void* d_ws, size_t ws_size,
                              hipStream_t stream){
  const float* src  = (const float*)d_in[0];
  const float* ne   = (const float*)d_in[1];
  const float* te   = (const float*)d_in[2];
  const float* de   = (const float*)d_in[3];
  const float* wp_g = (const float*)d_in[4];
  const float* bp_g = (const float*)d_in[5];
  const float* f1W_g= (const float*)d_in[6];
  const float* f1b_g= (const float*)d_in[7];
  const float* f2W_g= (const float*)d_in[8];
  const float* f2b_g= (const float*)d_in[9];
  const float* f3W_g= (const float*)d_in[10];
  const float* f3b_g= (const float*)d_in[11];
  const float* wp_u = (const float*)d_in[12];
  const float* bp_u = (const float*)d_in[13];
  const float* f1W_u= (const float*)d_in[14];
  const float* f1b_u= (const float*)d_in[15];
  const float* f2W_u= (const float*)d_in[16];
  const float* f2b_u= (const float*)d_in[17];
  const float* f3W_u= (const float*)d_in[18];
  const float* f3b_u= (const float*)d_in[19];
  const float* predW= (const float*)d_in[20];
  const float* predB= (const float*)d_in[21];
  const float* skipW= (const float*)d_in[22];
  const float* skipB= (const float*)d_in[23];

  float* ws   = (float*)d_ws;
  float* emb  = ws;
  float* cur  = emb  + (size_t)BB*TT*NN*EE;
  float* wg   = cur  + (size_t)2*TT*BB*NN;
  float* bg   = wg   + (size_t)NN*2*DIN*OG;
  float* wu   = bg   + (size_t)NN*OG;
  float* bu   = wu   + (size_t)NN*2*DIN*OU;
  float* h    = bu   + (size_t)NN*OU;
  float* xsg  = h    + (size_t)BB*NN*HH;
  float* xsu  = xsg  + (size_t)BB*NN*XSP;
  float* nv   = xsu  + (size_t)BB*NN*XSP;
  float* dbuf = nv   + (size_t)BB*NN*EE;
  float* parts= dbuf + (size_t)BB*NN;
  float* rbuf = parts+ (size_t)JS*BB*NP*XSP;
  float* outp = (float*)d_out;

  k_emb<<<(BB*TT*NN+255)/256, 256, 0, stream>>>(src, ne, te, de, emb, cur);

  for (int c=0;c<2;c++){
    hipMemsetAsync(h, 0, (size_t)BB*NN*HH*sizeof(float), stream);
    k_prep_w2<OG><<<dim3(2*DIN,2),256,0,stream>>>(ne, wp_g + (size_t)c*EE*2*DIN*OG, wg);
    k_prep_b<OG><<<(NN*OG+255)/256,256,0,stream>>>(ne, bp_g + (size_t)c*EE*OG, bg);
    k_prep_w2<OU><<<dim3(2*DIN,2),256,0,stream>>>(ne, wp_u + (size_t)c*EE*2*DIN*OU, wu);
    k_prep_b<OU><<<(NN*OU+255)/256,256,0,stream>>>(ne, bp_u + (size_t)c*EE*OU, bu);
    k_init<<<(BB*NN+255)/256,256,0,stream>>>(cur + (size_t)c*TT*BB*NN,
        f1W_g + c*16*DIN, f1b_g + c*16, f2W_g + c*2*16, f2b_g + c*2,
        f3W_g + c*EE*2, f3b_g + c*EE, emb, xsg, nv);
    for (int t=0;t<TT;t++){
      k_dsum<<<dim3(NC2,BB),256,0,stream>>>(nv, dbuf);
      k_xg2<<<dim3(NC2,JS,BB),256,0,stream>>>(nv, dbuf, xsg, parts);
      k_tr_gate<<<NN,256,0,stream>>>(wg, bg, parts, dbuf, xsg,
          cur + ((size_t)c*TT+t)*BB*NN, h, emb, t,
          f1W_u + c*16*DIN, f1b_u + c*16, f2W_u + c*2*16, f2b_u + c*2,
          f3W_u + c*EE*2, f3b_u + c*EE, rbuf, xsu, nv);
      k_dsum<<<dim3(NC2,BB),256,0,stream>>>(nv, dbuf);
      k_xg2<<<dim3(NC2,JS,BB),256,0,stream>>>(nv, dbuf, xsu, parts);
      k_tr_upd<<<NN,256,0,stream>>>(wu, bu, parts, dbuf, xsu, rbuf, h,
          cur, c, t, emb,
          f1W_g + c*16*DIN, f1b_g + c*16, f2W_g + c*2*16, f2b_g + c*2,
          f3W_g + c*EE*2, f3b_g + c*EE,
          xsg, nv, predW, predB, skipW, skipB, outp);
    }
  }
}